// Round 8
// baseline (1033.357 us; speedup 1.0000x reference)
//
#include <hip/hip_runtime.h>
#include <hip/hip_bf16.h>
#include <math.h>

// ODNet_att R8:
//  - gemm_bt: back to single-buffer 2-barrier loop (R6 structure).
//  - A staged via global_load_lds with XOR-swizzle (pre-swizzled global source,
//    linear LDS dest, swizzled ds_read) -> 16-way bank conflict eliminated.
//  - B operands read DIRECTLY global->register (L2-hot panels, no LDS).
//  - LDS 16KB/block.
// Everything else identical to the R7 passing kernel.

#define DEV __device__ __forceinline__

typedef __attribute__((ext_vector_type(4))) float  f32x4;
typedef __attribute__((ext_vector_type(4))) float  fvec4;
typedef __attribute__((ext_vector_type(8))) short  bf16x8;
typedef __attribute__((ext_vector_type(4))) unsigned short u16x4;

constexpr int BN_ = 32768;     // B*N = 64*512
constexpr int E_  = 262144;    // edges
constexpr long OUTSEC = 4194304; // 32768*128 per output section
constexpr long ZSZE = 25165824; // 32768*768 elements per branch ZCAT

DEV unsigned short f2bf(float f){
  union { float f; unsigned u; } v; v.f = f;
  unsigned r = (v.u + 0x7FFFu + ((v.u >> 16) & 1u)) >> 16;
  return (unsigned short)r;
}
DEV float b2f(unsigned short h){
  union { unsigned u; float f; } v; v.u = ((unsigned)h) << 16;
  return v.f;
}

// ---------------- graph build ----------------
__global__ __launch_bounds__(256) void histdeg_kernel(const int* __restrict__ ei,
    const float* __restrict__ ew, unsigned* __restrict__ cnt, float* __restrict__ deg){
  int e = blockIdx.x*256 + threadIdx.x;
  int d = ei[E_ + e];
  atomicAdd(&cnt[d], 1u);
  atomicAdd(&deg[d], ew[e]);
}

__global__ __launch_bounds__(1024) void scan_kernel(const unsigned* __restrict__ cnt,
                                                    unsigned* __restrict__ rowptr){
  __shared__ unsigned sm[1024];
  __shared__ unsigned carry;
  int tid = threadIdx.x;
  if (tid == 0) carry = 0;
  __syncthreads();
  for (int base = 0; base < BN_; base += 1024){
    unsigned v = cnt[base + tid];
    sm[tid] = v;
    __syncthreads();
    for (int off = 1; off < 1024; off <<= 1){
      unsigned t = (tid >= off) ? sm[tid - off] : 0u;
      __syncthreads();
      sm[tid] += t;
      __syncthreads();
    }
    rowptr[base + tid] = carry + sm[tid] - v;  // exclusive prefix
    __syncthreads();
    if (tid == 1023) carry += sm[1023];
    __syncthreads();
  }
  if (tid == 0) rowptr[BN_] = carry;
}

__global__ __launch_bounds__(256) void scatter_kernel(const int* __restrict__ ei,
    const float* __restrict__ ew, const unsigned* __restrict__ rowptr,
    unsigned* __restrict__ curs, unsigned* __restrict__ csrc, float* __restrict__ csrw){
  int e = blockIdx.x*256 + threadIdx.x;
  int d = ei[E_ + e];
  unsigned pos = atomicAdd(&curs[d], 1u);
  unsigned idx = rowptr[d] + pos;
  csrc[idx] = (unsigned)ei[e];
  csrw[idx] = ew[e];
}

// ---------------- propagation (z-batched over 3 branches) ----------------
template<int SRC>  // 0: read f32 input (per-z), 1: read bf16 from zcat
__global__ __launch_bounds__(256) void prop3_kernel(const float* __restrict__ x0,
    const float* __restrict__ x1, const float* __restrict__ x2,
    unsigned short* __restrict__ zcat,
    const unsigned* __restrict__ rowptr, const unsigned* __restrict__ csrc,
    const float* __restrict__ csrw, const float* __restrict__ deg){
  int node = blockIdx.x*4 + (threadIdx.x >> 6);
  int l = threadIdx.x & 63;
  int z = blockIdx.z;
  const float* xf = (z == 0) ? x0 : (z == 1) ? x1 : x2;
  const unsigned short* zin = zcat + z*ZSZE + 256;
  unsigned short* zout = zcat + z*ZSZE + (SRC == 0 ? 256 : 512);
  unsigned b0 = rowptr[node], b1 = rowptr[node + 1];
  float a0 = 0.f, a1 = 0.f, a2 = 0.f, a3 = 0.f;
  for (unsigned e = b0; e < b1; ++e){
    int s = csrc[e]; float w = csrw[e];
    if constexpr (SRC == 0){
      fvec4 v = *(const fvec4*)(xf + (long)s*256 + l*4);
      a0 += w*v[0]; a1 += w*v[1]; a2 += w*v[2]; a3 += w*v[3];
    } else {
      u16x4 v = *(const u16x4*)(zin + (long)s*768 + l*4);
      a0 += w*b2f(v[0]); a1 += w*b2f(v[1]); a2 += w*b2f(v[2]); a3 += w*b2f(v[3]);
    }
  }
  float dg = deg[node]; dg = dg > 1.f ? dg : 1.f;
  float inv = 1.f / dg;
  u16x4 o = { f2bf(a0*inv), f2bf(a1*inv), f2bf(a2*inv), f2bf(a3*inv) };
  *(u16x4*)(zout + (long)node*768 + l*4) = o;
}

// x (f32 [BN][256]) -> zcat cols 0:256 (bf16, row stride 768), z-batched
__global__ __launch_bounds__(256) void convx3_kernel(const float* __restrict__ x0,
    const float* __restrict__ x1, const float* __restrict__ x2,
    unsigned short* __restrict__ zcat){
  int id = blockIdx.x*256 + threadIdx.x;   // over 32768*64
  int z = blockIdx.z;
  const float* xf = (z == 0) ? x0 : (z == 1) ? x1 : x2;
  fvec4 v = ((const fvec4*)xf)[id];
  int m = id >> 6, c4 = id & 63;
  u16x4 o = { f2bf(v[0]), f2bf(v[1]), f2bf(v[2]), f2bf(v[3]) };
  *(u16x4*)(zcat + z*ZSZE + (long)m*768 + c4*4) = o;
}

// ---------------- weight prep ----------------
__global__ __launch_bounds__(256) void cvt_f2b_kernel(const float* __restrict__ s,
                                                      unsigned short* __restrict__ d, int n){
  int i = blockIdx.x*256 + threadIdx.x;
  if (i < n) d[i] = f2bf(s[i]);
}

// transpose+convert: src f32 [R][2^lgC] -> dst bf16 [2^lgC][R]
__global__ __launch_bounds__(256) void tcvt_kernel(const float* __restrict__ s,
    unsigned short* __restrict__ d, int lgC, int R){
  int id = blockIdx.x*256 + threadIdx.x;
  int r = id >> lgC, c = id & ((1 << lgC) - 1);
  d[(long)c*R + r] = f2bf(s[id]);
}

// Build BT[256][768], u/c INTERLEAVED, z-batched over the 3 branches.
// out-row n: j=n>>1; even n -> u_j (W_ru col 128+j), odd n -> c_j (W_c col j).
// k -> W row (k>>8)*384 + (k&255).
__global__ __launch_bounds__(256) void weff3_kernel(
    const float* __restrict__ Wru0, const float* __restrict__ Wru1, const float* __restrict__ Wru2,
    const float* __restrict__ bru0, const float* __restrict__ bru1, const float* __restrict__ bru2,
    const float* __restrict__ Wc0,  const float* __restrict__ Wc1,  const float* __restrict__ Wc2,
    const float* __restrict__ bc0,  const float* __restrict__ bc1,  const float* __restrict__ bc2,
    unsigned short* __restrict__ Weff, float* __restrict__ beff){
  int z = blockIdx.y;
  const float* Wru = (z == 0) ? Wru0 : (z == 1) ? Wru1 : Wru2;
  const float* bru = (z == 0) ? bru0 : (z == 1) ? bru1 : bru2;
  const float* Wc  = (z == 0) ? Wc0  : (z == 1) ? Wc1  : Wc2;
  const float* bc  = (z == 0) ? bc0  : (z == 1) ? bc1  : bc2;
  int id = blockIdx.x*256 + threadIdx.x;   // 256*768
  int n = id / 768, k = id % 768;
  int row = (k >> 8)*384 + (k & 255);
  int j = n >> 1;
  float w = ((n & 1) == 0) ? Wru[(long)row*256 + 128 + j] : Wc[(long)row*128 + j];
  Weff[(long)z*196608 + (long)n*768 + k] = f2bf(w);
  if (k == 0) beff[z*256 + n] = ((n & 1) == 0) ? bru[128 + j] : bc[j];
}

// PET4[(o>>2)*256 + b*4 + (o&3)] = pos_enc(b,o) + bhd[o]   (f32, [64]x[512] folded)
__global__ __launch_bounds__(256) void pe_kernel(const float* __restrict__ bhd,
                                                 float* __restrict__ PET4){
  int id = blockIdx.x*256 + threadIdx.x;   // 64*512
  int b = id >> 9, o = id & 511;
  float j2 = (float)(o & ~1);
  float ang = (float)b * expf(-j2 * (9.210340371976184f / 512.f)); // ln(1e4)
  float v = ((o & 1) ? cosf(ang) : sinf(ang)) + bhd[o];
  PET4[(o >> 2)*256 + b*4 + (o & 3)] = v;
}

// peq2[b][j] = bin[j] + sum_o PET(b,o) * Win[j][o]   (wave per j, lane = b)
__global__ __launch_bounds__(256) void peq2_kernel(const float* __restrict__ Win,
    const float* __restrict__ bin, const float* __restrict__ PET4, float* __restrict__ peq2){
  int j = blockIdx.x*4 + (threadIdx.x >> 6);
  int l = threadIdx.x & 63;
  float acc = 0.f;
  for (int o4 = 0; o4 < 128; ++o4){
    fvec4 wv = *(const fvec4*)(Win + (long)j*512 + o4*4);   // broadcast across lanes
    fvec4 pv = *(const fvec4*)(PET4 + o4*256 + l*4);        // coalesced
    acc += wv[0]*pv[0] + wv[1]*pv[1] + wv[2]*pv[2] + wv[3]*pv[3];
  }
  peq2[(long)l*1536 + j] = bin[j] + acc;
}

// beq[g] = bgate[g] + dot(Wgate[g,:], bout)
__global__ __launch_bounds__(128) void beq_kernel(const float* __restrict__ Wgt,
    const float* __restrict__ bout, const float* __restrict__ bgate, float* __restrict__ beq){
  int g = threadIdx.x;
  float s = bgate[g];
  for (int c = 0; c < 512; ++c) s += Wgt[(long)g*512 + c] * bout[c];
  beq[g] = s;
}

// ---------------- shared bf16 MFMA GEMM ----------------
// C[m][n] = scale * sum_k A[m][k]*Bt[n][k] (+bias) ; tiles 128x128, BK=64.
// A: global_load_lds w16, XOR-swizzled (source granule gg^=row&7, linear LDS
//    dest, same XOR on ds_read) -> conflict-free. B: direct global->register
//    bf16x8 loads (panels are L2-hot). LDS = 16KB. 2 barriers per K-tile.
// MODE 0: plain. MODE 1: attn scores. MODE 2: ctx (P@V^T). MODE 3: z-batched
//   plain (aOff=z*sA, bOff=z*sB, cOff=z*sC, bias+=z*256).
// EPI 0: f32. 2: bf16. 4: f32 + row remap (n,b)->(b*512+n).
// EPI 5: bf16 + per-(row&63) f32 row-table add (fused pe/bias for qkv).
// EPI 7: fused GRU: pair (u,c) via shfl_xor(1), store (1-sig(u))*tanh(c) f32.
template<int MODE, int EPI>
__global__ __launch_bounds__(256) void gemm_bt(
    const unsigned short* __restrict__ A, const unsigned short* __restrict__ Bt,
    float* __restrict__ Cf, unsigned short* __restrict__ Cb,
    int Ktot, int lda, int ldb, int ldc,
    long sA, long sB, long sC, int g0,
    const float* __restrict__ bias, const float* __restrict__ pe, float scale)
{
  __shared__ unsigned short As[128*64];
  const int tid = threadIdx.x;
  long aOff, bOff, cOff;
  if constexpr (MODE == 0 || MODE == 3){
    aOff = blockIdx.z * sA; bOff = blockIdx.z * sB; cOff = blockIdx.z * sC;
  } else if constexpr (MODE == 1){
    int g = g0 + blockIdx.z;
    long base = (long)(g >> 1)*1536 + (long)(g & 1)*256;
    aOff = base; bOff = base + 512; cOff = (long)blockIdx.z * 262144;
  } else {
    int g = g0 + blockIdx.z;
    aOff = (long)blockIdx.z * 262144;
    bOff = (long)g * 131072;
    cOff = (long)g * 256;
  }
  const int bm = blockIdx.y * 128, bn = blockIdx.x * 128;
  const int w = tid >> 6, l = tid & 63;
  const int wr = w >> 1, wc = w & 1;

  // A staging bases: thread handles granule c=(row,gg); global source uses
  // swizzled granule gg^(row&7); LDS dest linear (uniform base + lane*16).
  const unsigned short* aB[4];
  #pragma unroll
  for (int i = 0; i < 4; ++i){
    int c = tid + i*256;
    int row = c >> 3, gg = c & 7;
    int ggs = gg ^ (row & 7);
    aB[i] = A + aOff + (long)(bm + row)*lda + ggs*8;
  }
  // B per-lane row bases (direct global reads)
  const unsigned short* bR[4];
  #pragma unroll
  for (int ni = 0; ni < 4; ++ni)
    bR[ni] = Bt + bOff + (long)(bn + wc*64 + ni*16 + (l & 15))*ldb + (l >> 4)*8;
  // A fragment read offsets (swizzled): row = wr*64 + mi*16 + (l&15)
  int aRow[4];
  #pragma unroll
  for (int mi = 0; mi < 4; ++mi) aRow[mi] = wr*64 + mi*16 + (l & 15);

  f32x4 acc[4][4] = {};
  for (int kt = 0; kt < Ktot; kt += 64){
    #pragma unroll
    for (int i = 0; i < 4; ++i)
      __builtin_amdgcn_global_load_lds(
        (const __attribute__((address_space(1))) unsigned int*)(aB[i] + kt),
        (__attribute__((address_space(3))) unsigned int*)&As[(i*256 + w*64)*8], 16, 0, 0);
    __syncthreads();
    #pragma unroll
    for (int ks = 0; ks < 2; ++ks){
      bf16x8 aF[4], bF[4];
      #pragma unroll
      for (int ni = 0; ni < 4; ++ni)
        bF[ni] = *(const bf16x8*)(bR[ni] + kt + ks*32);
      #pragma unroll
      for (int mi = 0; mi < 4; ++mi){
        int r = aRow[mi];
        int gr = (ks*4 + (l >> 4)) ^ (r & 7);
        aF[mi] = *(const bf16x8*)(&As[r*64 + gr*8]);
      }
      #pragma unroll
      for (int mi = 0; mi < 4; ++mi)
        #pragma unroll
        for (int ni = 0; ni < 4; ++ni)
          acc[mi][ni] = __builtin_amdgcn_mfma_f32_16x16x32_bf16(aF[mi], bF[ni], acc[mi][ni], 0, 0, 0);
    }
    __syncthreads();
  }
  // D layout: col = lane&15, row = (lane>>4)*4 + j  (m89-verified)
  #pragma unroll
  for (int mi = 0; mi < 4; ++mi){
    #pragma unroll
    for (int ni = 0; ni < 4; ++ni){
      int col = bn + wc*64 + ni*16 + (l & 15);
      int row0 = bm + wr*64 + mi*16 + ((l >> 4) << 2);
      #pragma unroll
      for (int j = 0; j < 4; ++j){
        int row = row0 + j;
        float v = acc[mi][ni][j] * scale;
        if (bias){
          if constexpr (MODE == 3) v += bias[(int)blockIdx.z*256 + col];
          else v += bias[col];
        }
        if constexpr (EPI == 5) v += pe[((row & 63) * 1536) + col];
        if constexpr (EPI == 0){
          Cf[cOff + (long)row*ldc + col] = v;
        } else if constexpr (EPI == 4){
          long orow = (long)(row & 63)*512 + (row >> 6);
          Cf[orow*ldc + col] = v;
        } else if constexpr (EPI == 7){
          float other = __shfl_xor(v, 1);
          if (!(l & 1)){
            float uu = 1.f / (1.f + expf(-v));
            Cf[cOff + (long)row*ldc + (col >> 1)] = (1.f - uu) * tanhf(other);
          }
        } else {
          Cb[cOff + (long)row*ldc + col] = f2bf(v);
        }
      }
    }
  }
}

// ---------------- glue ----------------
// Afus[(a*256 + rg)*64 + b][c] = sec[(b*512 + 2c + a)*128 + (rg&127)]
//   sec = hs (rg<128, out+2*OUTSEC) or hl (rg>=128, out+1*OUTSEC)
// LDS-transpose: coalesced f32 reads over r, coalesced bf16 writes over c.
// grid (4, 2, 64): cq = c-chunk of 64, a, b.
__global__ __launch_bounds__(256) void afus_kernel(const float* __restrict__ out,
                                                   unsigned short* __restrict__ Afus){
  __shared__ float sm[64][132];
  int cq = blockIdx.x, a = blockIdx.y, b = blockIdx.z;
  int tid = threadIdx.x;
  #pragma unroll
  for (int half = 0; half < 2; ++half){
    const float* sec = out + (half ? 1 : 2)*OUTSEC;   // hs then hl
    int cl = tid >> 2, r0 = (tid & 3)*4;              // load map
    long srow = ((long)b*512 + 2*(cq*64 + cl) + a)*128;
    #pragma unroll
    for (int it = 0; it < 8; ++it){
      int r = r0 + it*16;
      fvec4 v = *(const fvec4*)(sec + srow + r);
      *(fvec4*)&sm[cl][r] = v;
    }
    __syncthreads();
    int r = tid >> 1;                                  // write map
    int c0 = (tid & 1)*32;
    long mrow = ((long)a*256 + half*128 + r)*64 + b;
    unsigned short* dst = Afus + mrow*256 + cq*64 + c0;
    #pragma unroll
    for (int jj = 0; jj < 8; ++jj){
      int c = c0 + jj*4;
      u16x4 o = { f2bf(sm[c][r]), f2bf(sm[c+1][r]), f2bf(sm[c+2][r]), f2bf(sm[c+3][r]) };
      *(u16x4*)(dst + jj*4) = o;
    }
    __syncthreads();
  }
}

// vT[g=(b,h)][d][t] = qkv[t*64+b][1024 + h*256 + d]  (64x64 LDS transpose tiles)
__global__ __launch_bounds__(256) void vt_kernel(const unsigned short* __restrict__ qkv,
                                                 unsigned short* __restrict__ vT){
  int g = blockIdx.y; int b = g >> 1, h = g & 1;
  int tt = blockIdx.x & 7, dt = blockIdx.x >> 3;
  __shared__ unsigned short sm[64][65];
  int lrow = threadIdx.x >> 6, lcol = threadIdx.x & 63;
  const unsigned short* src = qkv + (long)b*1536 + 1024 + (long)h*256 + dt*64;
  #pragma unroll
  for (int i = 0; i < 16; ++i){
    int t = tt*64 + lrow + i*4;
    sm[lrow + i*4][lcol] = src[(long)t*98304 + lcol];
  }
  __syncthreads();
  unsigned short* dstp = vT + (long)g*131072 + (long)(dt*64)*512 + tt*64;
  #pragma unroll
  for (int i = 0; i < 16; ++i){
    int d = lrow + i*4;
    dstp[(long)d*512 + lcol] = sm[lcol][d];
  }
}

// in-place row softmax over bf16 scores [65536 rows][512]
__global__ __launch_bounds__(256) void smax_kernel(unsigned short* __restrict__ S){
  long row = (long)blockIdx.x*4 + (threadIdx.x >> 6);
  int l = threadIdx.x & 63;
  unsigned short* p = S + row*512 + l*8;
  bf16x8 v = *(const bf16x8*)p;
  float f[8];
  #pragma unroll
  for (int j = 0; j < 8; ++j) f[j] = b2f((unsigned short)v[j]);
  float m = f[0];
  #pragma unroll
  for (int j = 1; j < 8; ++j) m = fmaxf(m, f[j]);
  #pragma unroll
  for (int off = 32; off; off >>= 1) m = fmaxf(m, __shfl_xor(m, off));
  float s = 0.f;
  #pragma unroll
  for (int j = 0; j < 8; ++j){ f[j] = expf(f[j] - m); s += f[j]; }
  #pragma unroll
  for (int off = 32; off; off >>= 1) s += __shfl_xor(s, off);
  float inv = 1.f / s;
  bf16x8 o;
  #pragma unroll
  for (int j = 0; j < 8; ++j) o[j] = (short)f2bf(f[j]*inv);
  *(bf16x8*)p = o;
}

// ---------------- host ----------------
extern "C" void kernel_launch(void* const* d_in, const int* in_sizes, int n_in,
                              void* d_out, int out_size, void* d_ws, size_t ws_size,
                              hipStream_t stream)
{
  (void)in_sizes; (void)n_in; (void)out_size;
  constexpr long MB = 1l << 20;
  if (ws_size < 200*MB) return;  // layout needs 200 MiB; fail loudly via absmax

  const float* x0 = (const float*)d_in[0];
  const float* x1 = (const float*)d_in[1];
  const float* x2 = (const float*)d_in[2];
  const int*   ei = (const int*)d_in[3];
  const float* ew = (const float*)d_in[4];
  const float* Whd  = (const float*)d_in[17]; const float* bhd   = (const float*)d_in[18];
  const float* Win  = (const float*)d_in[19]; const float* bin   = (const float*)d_in[20];
  const float* Wout = (const float*)d_in[21]; const float* bout  = (const float*)d_in[22];
  const float* Wgt  = (const float*)d_in[23]; const float* bgate = (const float*)d_in[24];
  float* out = (float*)d_out;
  char* ws = (char*)d_ws;

  float*    deg    = (float*)(ws + 0);
  unsigned* cnt    = (unsigned*)(ws + 131072);
  unsigned* rowptr = (unsigned*)(ws + 262144);
  unsigned* curs   = (unsigned*)(ws + 524288);
  unsigned* csrc   = (unsigned*)(ws + 786432);
  float*    csrw   = (float*)(ws + 1835008);
  unsigned short* Weff = (unsigned short*)(ws + 2883584);   // 3 x [256][768]
  float*    beff   = (float*)(ws + 4063232);                // 3 x 256 f32
  float*    beq    = (float*)(ws + 4194304);                // 128 f32
  unsigned short* WIN   = (unsigned short*)(ws + 4456448);  // [1536][512] bf16
  unsigned short* WGTB  = (unsigned short*)(ws + 6029312);  // [128][512] bf16
  unsigned short* WHDT  = (unsigned short*)(ws + 6160384);  // [256][512] bf16 (Whd^T)
  unsigned short* WOUTT = (unsigned short*)(ws + 6422528);  // [512][512] bf16 (Wout^T)
  unsigned short* Wq2t  = (unsigned short*)(ws + 6946816);  // [1536][256] bf16 (Win*Whd)
  unsigned short* Weqt  = (unsigned short*)(ws + 7733248);  // [128][512] bf16 (Wgate*Wout)
  float*    PET4   = (float*)(ws + 7864320);                // [128][64][4] f32 (pe+bhd)^T
  float*    PEQ2   = (float*)(ws + 7995392);                // [64][1536] f32 (ends at 8MB)
  unsigned short* ZCAT3 = (unsigned short*)(ws + 40*MB);    // 3 x [32768][768] (40..184)
  unsigned short* AFUS  = (unsigned short*)(ws + 8*MB);     // [32768][256] 16MB (8..24)
  unsigned short* QKV   = (unsigned short*)(ws + 40*MB);    // [32768][1536] (40..136)
  unsigned short* VT    = (unsigned short*)(ws + 8*MB);     // [128][256][512] (8..40)
  unsigned short* SCOREB= (unsigned short*)(ws + 136*MB);   // [128][512][512] bf16 (136..200)
  unsigned short* CTX   = (unsigned short*)(ws + 40*MB);    // [512][32768] bf16 (40..72)

  // graph build
  hipMemsetAsync(deg,  0, 131072, stream);
  hipMemsetAsync(cnt,  0, 131072, stream);
  hipMemsetAsync(curs, 0, 131072, stream);
  histdeg_kernel<<<1024, 256, 0, stream>>>(ei, ew, cnt, deg);
  scan_kernel<<<1, 1024, 0, stream>>>(cnt, rowptr);
  scatter_kernel<<<1024, 256, 0, stream>>>(ei, ew, rowptr, curs, csrc, csrw);

  // weight prep
  weff3_kernel<<<dim3(768,3), 256, 0, stream>>>(
      (const float*)d_in[5], (const float*)d_in[9],  (const float*)d_in[13],
      (const float*)d_in[6], (const float*)d_in[10], (const float*)d_in[14],
      (const float*)d_in[7], (const float*)d_in[11], (const float*)d_in[15],
      (const float*)d_in[8], (const float*)d_in[12], (const float*)d_in[16],
      Weff, beff);
  cvt_f2b_kernel<<<3072, 256, 0, stream>>>(Win, WIN,  786432);
  cvt_f2b_kernel<<<256,  256, 0, stream>>>(Wgt, WGTB, 65536);
  tcvt_kernel<<<512,  256, 0, stream>>>(Whd,  WHDT,  8, 512);   // [512][256] -> [256][512]
  tcvt_kernel<<<1024, 256, 0, stream>>>(Wout, WOUTT, 9, 512);   // [512][512] -> ^T
  pe_kernel<<<128, 256, 0, stream>>>(bhd, PET4);

  // fused-weight precompute
  gemm_bt<0,2><<<dim3(2,12,1), 256, 0, stream>>>(WIN, WHDT, nullptr, Wq2t,
      512, 512, 512, 256, 0,0,0, 0, nullptr, nullptr, 1.0f);
  gemm_bt<0,2><<<dim3(4,1,1), 256, 0, stream>>>(WGTB, WOUTT, nullptr, Weqt,
      512, 512, 512, 512, 0,0,0, 0, nullptr, nullptr, 1.0f);
  peq2_kernel<<<384, 256, 0, stream>>>(Win, bin, PET4, PEQ2);
  beq_kernel<<<1, 128, 0, stream>>>(Wgt, bout, bgate, beq);

  // branches (z-batched): hop features then fused GEMM+GRU-activation -> out 0..2
  convx3_kernel<<<dim3(8192,1,3), 256, 0, stream>>>(x0, x1, x2, ZCAT3);
  prop3_kernel<0><<<dim3(8192,1,3), 256, 0, stream>>>(x0, x1, x2, ZCAT3,
                                                      rowptr, csrc, csrw, deg);
  prop3_kernel<1><<<dim3(8192,1,3), 256, 0, stream>>>(x0, x1, x2, ZCAT3,
                                                      rowptr, csrc, csrw, deg);
  gemm_bt<3,7><<<dim3(2,256,3), 256, 0, stream>>>(ZCAT3, Weff, out, nullptr,
      768, 768, 768, 128, ZSZE, 196608, OUTSEC, 0, beff, nullptr, 1.0f);

  // fusion gather, then fused uh+qkv GEMM (K=256, pe/bias row-table in epilogue)
  afus_kernel<<<dim3(4,2,64), 256, 0, stream>>>(out, AFUS);
  gemm_bt<0,5><<<dim3(12,256,1), 256, 0, stream>>>(AFUS, Wq2t, nullptr, QKV,
      256, 256, 256, 1536, 0,0,0, 0, nullptr, PEQ2, 1.0f);
  vt_kernel<<<dim3(32,128), 256, 0, stream>>>(QKV, VT);

  // attention, single shot z=128: bf16 scores -> in-place softmax -> ctx
  gemm_bt<1,2><<<dim3(4,4,128), 256, 0, stream>>>(QKV, QKV, nullptr, SCOREB,
      256, 98304, 98304, 512, 0,0,0, 0, nullptr, nullptr, 0.0625f);
  smax_kernel<<<16384, 256, 0, stream>>>(SCOREB);
  gemm_bt<2,2><<<dim3(2,4,128), 256, 0, stream>>>(SCOREB, VT, nullptr, CTX,
      512, 512, 512, 32768, 0,0,0, 0, nullptr, nullptr, 1.0f);

  // fused wout+wgate output GEMM (row remap (n,b) -> b*512+n in epilogue)
  gemm_bt<0,4><<<dim3(1,256,1), 256, 0, stream>>>(CTX, Weqt, out + 3*OUTSEC, nullptr,
      512, 512, 512, 128, 0,0,0, 0, beq, nullptr, 1.0f);
}

// Round 9
// 865.646 us; speedup vs baseline: 1.1937x; 1.1937x over previous
//
#include <hip/hip_runtime.h>
#include <hip/hip_bf16.h>
#include <math.h>

// ODNet_att R9:
//  - gemm_bt: reverted to the R6 inner loop (single-buffer, both A/B staged via
//    global_load_lds w16, 2 barriers/K-tile) -- best measured (152us branch).
//  - NEW: XCD-aware work swizzle (T1) on all large GEMM dispatches (bijective,
//    grids %8==0): co-locates blocks sharing an A-panel on one XCD L2.
//  - prop3: hop-0 gathers bf16 from ZCAT (half the bytes of f32 x); edge loop
//    2x-unrolled (issue both row-gathers before their FMAs).

#define DEV __device__ __forceinline__

typedef __attribute__((ext_vector_type(4))) float  f32x4;
typedef __attribute__((ext_vector_type(4))) float  fvec4;
typedef __attribute__((ext_vector_type(8))) short  bf16x8;
typedef __attribute__((ext_vector_type(4))) unsigned short u16x4;

constexpr int BN_ = 32768;     // B*N = 64*512
constexpr int E_  = 262144;    // edges
constexpr long OUTSEC = 4194304; // 32768*128 per output section
constexpr long ZSZE = 25165824; // 32768*768 elements per branch ZCAT

DEV unsigned short f2bf(float f){
  union { float f; unsigned u; } v; v.f = f;
  unsigned r = (v.u + 0x7FFFu + ((v.u >> 16) & 1u)) >> 16;
  return (unsigned short)r;
}
DEV float b2f(unsigned short h){
  union { unsigned u; float f; } v; v.u = ((unsigned)h) << 16;
  return v.f;
}

// ---------------- graph build ----------------
__global__ __launch_bounds__(256) void histdeg_kernel(const int* __restrict__ ei,
    const float* __restrict__ ew, unsigned* __restrict__ cnt, float* __restrict__ deg){
  int e = blockIdx.x*256 + threadIdx.x;
  int d = ei[E_ + e];
  atomicAdd(&cnt[d], 1u);
  atomicAdd(&deg[d], ew[e]);
}

__global__ __launch_bounds__(1024) void scan_kernel(const unsigned* __restrict__ cnt,
                                                    unsigned* __restrict__ rowptr){
  __shared__ unsigned sm[1024];
  __shared__ unsigned carry;
  int tid = threadIdx.x;
  if (tid == 0) carry = 0;
  __syncthreads();
  for (int base = 0; base < BN_; base += 1024){
    unsigned v = cnt[base + tid];
    sm[tid] = v;
    __syncthreads();
    for (int off = 1; off < 1024; off <<= 1){
      unsigned t = (tid >= off) ? sm[tid - off] : 0u;
      __syncthreads();
      sm[tid] += t;
      __syncthreads();
    }
    rowptr[base + tid] = carry + sm[tid] - v;  // exclusive prefix
    __syncthreads();
    if (tid == 1023) carry += sm[1023];
    __syncthreads();
  }
  if (tid == 0) rowptr[BN_] = carry;
}

__global__ __launch_bounds__(256) void scatter_kernel(const int* __restrict__ ei,
    const float* __restrict__ ew, const unsigned* __restrict__ rowptr,
    unsigned* __restrict__ curs, unsigned* __restrict__ csrc, float* __restrict__ csrw){
  int e = blockIdx.x*256 + threadIdx.x;
  int d = ei[E_ + e];
  unsigned pos = atomicAdd(&curs[d], 1u);
  unsigned idx = rowptr[d] + pos;
  csrc[idx] = (unsigned)ei[e];
  csrw[idx] = ew[e];
}

// ---------------- propagation (z-batched over 3 branches) ----------------
// SRC 0: gather hop-0 bf16 (zcat cols 0:256, written by convx3) -> cols 256:512
// SRC 1: gather hop-1 bf16 (cols 256:512) -> cols 512:768
template<int SRC>
__global__ __launch_bounds__(256) void prop3_kernel(unsigned short* __restrict__ zcat,
    const unsigned* __restrict__ rowptr, const unsigned* __restrict__ csrc,
    const float* __restrict__ csrw, const float* __restrict__ deg){
  int node = blockIdx.x*4 + (threadIdx.x >> 6);
  int l = threadIdx.x & 63;
  int z = blockIdx.z;
  const unsigned short* zin = zcat + z*ZSZE + (SRC == 0 ? 0 : 256);
  unsigned short* zout = zcat + z*ZSZE + (SRC == 0 ? 256 : 512);
  unsigned b0 = rowptr[node], b1 = rowptr[node + 1];
  float a0 = 0.f, a1 = 0.f, a2 = 0.f, a3 = 0.f;
  unsigned e = b0;
  for (; e + 2 <= b1; e += 2){
    int s0 = csrc[e];     float w0 = csrw[e];
    int s1 = csrc[e + 1]; float w1 = csrw[e + 1];
    u16x4 v0 = *(const u16x4*)(zin + (long)s0*768 + l*4);
    u16x4 v1 = *(const u16x4*)(zin + (long)s1*768 + l*4);
    a0 += w0*b2f(v0[0]) + w1*b2f(v1[0]);
    a1 += w0*b2f(v0[1]) + w1*b2f(v1[1]);
    a2 += w0*b2f(v0[2]) + w1*b2f(v1[2]);
    a3 += w0*b2f(v0[3]) + w1*b2f(v1[3]);
  }
  if (e < b1){
    int s = csrc[e]; float w = csrw[e];
    u16x4 v = *(const u16x4*)(zin + (long)s*768 + l*4);
    a0 += w*b2f(v[0]); a1 += w*b2f(v[1]); a2 += w*b2f(v[2]); a3 += w*b2f(v[3]);
  }
  float dg = deg[node]; dg = dg > 1.f ? dg : 1.f;
  float inv = 1.f / dg;
  u16x4 o = { f2bf(a0*inv), f2bf(a1*inv), f2bf(a2*inv), f2bf(a3*inv) };
  *(u16x4*)(zout + (long)node*768 + l*4) = o;
}

// x (f32 [BN][256]) -> zcat cols 0:256 (bf16, row stride 768), z-batched
__global__ __launch_bounds__(256) void convx3_kernel(const float* __restrict__ x0,
    const float* __restrict__ x1, const float* __restrict__ x2,
    unsigned short* __restrict__ zcat){
  int id = blockIdx.x*256 + threadIdx.x;   // over 32768*64
  int z = blockIdx.z;
  const float* xf = (z == 0) ? x0 : (z == 1) ? x1 : x2;
  fvec4 v = ((const fvec4*)xf)[id];
  int m = id >> 6, c4 = id & 63;
  u16x4 o = { f2bf(v[0]), f2bf(v[1]), f2bf(v[2]), f2bf(v[3]) };
  *(u16x4*)(zcat + z*ZSZE + (long)m*768 + c4*4) = o;
}

// ---------------- weight prep ----------------
__global__ __launch_bounds__(256) void cvt_f2b_kernel(const float* __restrict__ s,
                                                      unsigned short* __restrict__ d, int n){
  int i = blockIdx.x*256 + threadIdx.x;
  if (i < n) d[i] = f2bf(s[i]);
}

// transpose+convert: src f32 [R][2^lgC] -> dst bf16 [2^lgC][R]
__global__ __launch_bounds__(256) void tcvt_kernel(const float* __restrict__ s,
    unsigned short* __restrict__ d, int lgC, int R){
  int id = blockIdx.x*256 + threadIdx.x;
  int r = id >> lgC, c = id & ((1 << lgC) - 1);
  d[(long)c*R + r] = f2bf(s[id]);
}

// Build BT[256][768], u/c INTERLEAVED, z-batched over the 3 branches.
__global__ __launch_bounds__(256) void weff3_kernel(
    const float* __restrict__ Wru0, const float* __restrict__ Wru1, const float* __restrict__ Wru2,
    const float* __restrict__ bru0, const float* __restrict__ bru1, const float* __restrict__ bru2,
    const float* __restrict__ Wc0,  const float* __restrict__ Wc1,  const float* __restrict__ Wc2,
    const float* __restrict__ bc0,  const float* __restrict__ bc1,  const float* __restrict__ bc2,
    unsigned short* __restrict__ Weff, float* __restrict__ beff){
  int z = blockIdx.y;
  const float* Wru = (z == 0) ? Wru0 : (z == 1) ? Wru1 : Wru2;
  const float* bru = (z == 0) ? bru0 : (z == 1) ? bru1 : bru2;
  const float* Wc  = (z == 0) ? Wc0  : (z == 1) ? Wc1  : Wc2;
  const float* bc  = (z == 0) ? bc0  : (z == 1) ? bc1  : bc2;
  int id = blockIdx.x*256 + threadIdx.x;   // 256*768
  int n = id / 768, k = id % 768;
  int row = (k >> 8)*384 + (k & 255);
  int j = n >> 1;
  float w = ((n & 1) == 0) ? Wru[(long)row*256 + 128 + j] : Wc[(long)row*128 + j];
  Weff[(long)z*196608 + (long)n*768 + k] = f2bf(w);
  if (k == 0) beff[z*256 + n] = ((n & 1) == 0) ? bru[128 + j] : bc[j];
}

// PET4[(o>>2)*256 + b*4 + (o&3)] = pos_enc(b,o) + bhd[o]
__global__ __launch_bounds__(256) void pe_kernel(const float* __restrict__ bhd,
                                                 float* __restrict__ PET4){
  int id = blockIdx.x*256 + threadIdx.x;   // 64*512
  int b = id >> 9, o = id & 511;
  float j2 = (float)(o & ~1);
  float ang = (float)b * expf(-j2 * (9.210340371976184f / 512.f)); // ln(1e4)
  float v = ((o & 1) ? cosf(ang) : sinf(ang)) + bhd[o];
  PET4[(o >> 2)*256 + b*4 + (o & 3)] = v;
}

// peq2[b][j] = bin[j] + sum_o PET(b,o) * Win[j][o]   (wave per j, lane = b)
__global__ __launch_bounds__(256) void peq2_kernel(const float* __restrict__ Win,
    const float* __restrict__ bin, const float* __restrict__ PET4, float* __restrict__ peq2){
  int j = blockIdx.x*4 + (threadIdx.x >> 6);
  int l = threadIdx.x & 63;
  float acc = 0.f;
  for (int o4 = 0; o4 < 128; ++o4){
    fvec4 wv = *(const fvec4*)(Win + (long)j*512 + o4*4);   // broadcast across lanes
    fvec4 pv = *(const fvec4*)(PET4 + o4*256 + l*4);        // coalesced
    acc += wv[0]*pv[0] + wv[1]*pv[1] + wv[2]*pv[2] + wv[3]*pv[3];
  }
  peq2[(long)l*1536 + j] = bin[j] + acc;
}

// beq[g] = bgate[g] + dot(Wgate[g,:], bout)
__global__ __launch_bounds__(128) void beq_kernel(const float* __restrict__ Wgt,
    const float* __restrict__ bout, const float* __restrict__ bgate, float* __restrict__ beq){
  int g = threadIdx.x;
  float s = bgate[g];
  for (int c = 0; c < 512; ++c) s += Wgt[(long)g*512 + c] * bout[c];
  beq[g] = s;
}

// ---------------- shared bf16 MFMA GEMM (R6 structure + XCD swizzle) ----------
// C[m][n] = scale * sum_k A[m][k]*Bt[n][k] (+bias) ; tiles 128x128, BK=64.
// Staging: global_load_lds width=16, single buffer, 2 barriers per K-tile.
// SWZ=1: bijective XCD work swizzle (requires total grid % 8 == 0).
// MODE 0: plain. MODE 1: attn scores. MODE 2: ctx (P@V^T). MODE 3: z-batched.
// EPI 0: f32. 2: bf16. 4: f32 + row remap. 5: bf16 + row-table add. 7: GRU.
template<int MODE, int EPI, int SWZ>
__global__ __launch_bounds__(256) void gemm_bt(
    const unsigned short* __restrict__ A, const unsigned short* __restrict__ Bt,
    float* __restrict__ Cf, unsigned short* __restrict__ Cb,
    int Ktot, int lda, int ldb, int ldc,
    long sA, long sB, long sC, int g0,
    const float* __restrict__ bias, const float* __restrict__ pe, float scale)
{
  __shared__ unsigned short As[128*64];
  __shared__ unsigned short Bs[128*64];
  const int tid = threadIdx.x;
  int bx = blockIdx.x, by = blockIdx.y, bzi = blockIdx.z;
  if constexpr (SWZ){
    int gx = gridDim.x, gy = gridDim.y;
    int nwg = gx*gy*(int)gridDim.z;
    int wid = (bzi*gy + by)*gx + bx;
    int swz = (wid & 7)*(nwg >> 3) + (wid >> 3);
    bx = swz % gx; int rem = swz / gx;
    by = rem % gy; bzi = rem / gy;
  }
  long aOff, bOff, cOff;
  if constexpr (MODE == 0 || MODE == 3){
    aOff = bzi * sA; bOff = bzi * sB; cOff = bzi * sC;
  } else if constexpr (MODE == 1){
    int g = g0 + bzi;
    long base = (long)(g >> 1)*1536 + (long)(g & 1)*256;
    aOff = base; bOff = base + 512; cOff = (long)bzi * 262144;
  } else {
    int g = g0 + bzi;
    aOff = (long)bzi * 262144;
    bOff = (long)g * 131072;
    cOff = (long)g * 256;
  }
  const int bm = by * 128, bn = bx * 128;
  const int w = tid >> 6, l = tid & 63;
  const int wr = w >> 1, wc = w & 1;

  // per-lane global staging bases (element offsets); LDS dest is linear in c
  const unsigned short* aB[4];
  const unsigned short* bB[4];
  #pragma unroll
  for (int i = 0; i < 4; ++i){
    int c = tid + i*256;
    int row = c >> 3, gg = c & 7;
    aB[i] = A  + aOff + (long)(bm + row)*lda + gg*8;
    bB[i] = Bt + bOff + (long)(bn + row)*ldb + gg*8;
  }

  f32x4 acc[4][4] = {};
  for (int kt = 0; kt < Ktot; kt += 64){
    #pragma unroll
    for (int i = 0; i < 4; ++i){
      __builtin_amdgcn_global_load_lds(
        (const __attribute__((address_space(1))) unsigned int*)(aB[i] + kt),
        (__attribute__((address_space(3))) unsigned int*)&As[(i*256 + w*64)*8], 16, 0, 0);
      __builtin_amdgcn_global_load_lds(
        (const __attribute__((address_space(1))) unsigned int*)(bB[i] + kt),
        (__attribute__((address_space(3))) unsigned int*)&Bs[(i*256 + w*64)*8], 16, 0, 0);
    }
    __syncthreads();
    #pragma unroll
    for (int ks = 0; ks < 2; ++ks){
      bf16x8 aF[4], bF[4];
      #pragma unroll
      for (int mi = 0; mi < 4; ++mi)
        aF[mi] = *(const bf16x8*)(&As[(wr*64 + mi*16 + (l & 15))*64 + ks*32 + (l >> 4)*8]);
      #pragma unroll
      for (int ni = 0; ni < 4; ++ni)
        bF[ni] = *(const bf16x8*)(&Bs[(wc*64 + ni*16 + (l & 15))*64 + ks*32 + (l >> 4)*8]);
      #pragma unroll
      for (int mi = 0; mi < 4; ++mi)
        #pragma unroll
        for (int ni = 0; ni < 4; ++ni)
          acc[mi][ni] = __builtin_amdgcn_mfma_f32_16x16x32_bf16(aF[mi], bF[ni], acc[mi][ni], 0, 0, 0);
    }
    __syncthreads();
  }
  // D layout: col = lane&15, row = (lane>>4)*4 + j  (m89-verified)
  #pragma unroll
  for (int mi = 0; mi < 4; ++mi){
    #pragma unroll
    for (int ni = 0; ni < 4; ++ni){
      int col = bn + wc*64 + ni*16 + (l & 15);
      int row0 = bm + wr*64 + mi*16 + ((l >> 4) << 2);
      #pragma unroll
      for (int j = 0; j < 4; ++j){
        int row = row0 + j;
        float v = acc[mi][ni][j] * scale;
        if (bias){
          if constexpr (MODE == 3) v += bias[bzi*256 + col];
          else v += bias[col];
        }
        if constexpr (EPI == 5) v += pe[((row & 63) * 1536) + col];
        if constexpr (EPI == 0){
          Cf[cOff + (long)row*ldc + col] = v;
        } else if constexpr (EPI == 4){
          long orow = (long)(row & 63)*512 + (row >> 6);
          Cf[orow*ldc + col] = v;
        } else if constexpr (EPI == 7){
          float other = __shfl_xor(v, 1);
          if (!(l & 1)){
            float uu = 1.f / (1.f + expf(-v));
            Cf[cOff + (long)row*ldc + (col >> 1)] = (1.f - uu) * tanhf(other);
          }
        } else {
          Cb[cOff + (long)row*ldc + col] = f2bf(v);
        }
      }
    }
  }
}

// ---------------- glue ----------------
// Afus[(a*256 + rg)*64 + b][c] = sec[(b*512 + 2c + a)*128 + (rg&127)]
__global__ __launch_bounds__(256) void afus_kernel(const float* __restrict__ out,
                                                   unsigned short* __restrict__ Afus){
  __shared__ float sm[64][132];
  int cq = blockIdx.x, a = blockIdx.y, b = blockIdx.z;
  int tid = threadIdx.x;
  #pragma unroll
  for (int half = 0; half < 2; ++half){
    const float* sec = out + (half ? 1 : 2)*OUTSEC;   // hs then hl
    int cl = tid >> 2, r0 = (tid & 3)*4;              // load map
    long srow = ((long)b*512 + 2*(cq*64 + cl) + a)*128;
    #pragma unroll
    for (int it = 0; it < 8; ++it){
      int r = r0 + it*16;
      fvec4 v = *(const fvec4*)(sec + srow + r);
      *(fvec4*)&sm[cl][r] = v;
    }
    __syncthreads();
    int r = tid >> 1;                                  // write map
    int c0 = (tid & 1)*32;
    long mrow = ((long)a*256 + half*128 + r)*64 + b;
    unsigned short* dst = Afus + mrow*256 + cq*64 + c0;
    #pragma unroll
    for (int jj = 0; jj < 8; ++jj){
      int c = c0 + jj*4;
      u16x4 o = { f2bf(sm[c][r]), f2bf(sm[c+1][r]), f2bf(sm[c+2][r]), f2bf(sm[c+3][r]) };
      *(u16x4*)(dst + jj*4) = o;
    }
    __syncthreads();
  }
}

// vT[g=(b,h)][d][t] = qkv[t*64+b][1024 + h*256 + d]  (64x64 LDS transpose tiles)
__global__ __launch_bounds__(256) void vt_kernel(const unsigned short* __restrict__ qkv,
                                                 unsigned short* __restrict__ vT){
  int g = blockIdx.y; int b = g >> 1, h = g & 1;
  int tt = blockIdx.x & 7, dt = blockIdx.x >> 3;
  __shared__ unsigned short sm[64][65];
  int lrow = threadIdx.x >> 6, lcol = threadIdx.x & 63;
  const unsigned short* src = qkv + (long)b*1536 + 1024 + (long)h*256 + dt*64;
  #pragma unroll
  for (int i = 0; i < 16; ++i){
    int t = tt*64 + lrow + i*4;
    sm[lrow + i*4][lcol] = src[(long)t*98304 + lcol];
  }
  __syncthreads();
  unsigned short* dstp = vT + (long)g*131072 + (long)(dt*64)*512 + tt*64;
  #pragma unroll
  for (int i = 0; i < 16; ++i){
    int d = lrow + i*4;
    dstp[(long)d*512 + lcol] = sm[lcol][d];
  }
}

// in-place row softmax over bf16 scores [65536 rows][512]
__global__ __launch_bounds__(256) void smax_kernel(unsigned short* __restrict__ S){
  long row = (long)blockIdx.x*4 + (threadIdx.x >> 6);
  int l = threadIdx.x & 63;
  unsigned short* p = S + row*512 + l*8;
  bf16x8 v = *(const bf16x8*)p;
  float f[8];
  #pragma unroll
  for (int j = 0; j < 8; ++j) f[j] = b2f((unsigned short)v[j]);
  float m = f[0];
  #pragma unroll
  for (int j = 1; j < 8; ++j) m = fmaxf(m, f[j]);
  #pragma unroll
  for (int off = 32; off; off >>= 1) m = fmaxf(m, __shfl_xor(m, off));
  float s = 0.f;
  #pragma unroll
  for (int j = 0; j < 8; ++j){ f[j] = expf(f[j] - m); s += f[j]; }
  #pragma unroll
  for (int off = 32; off; off >>= 1) s += __shfl_xor(s, off);
  float inv = 1.f / s;
  bf16x8 o;
  #pragma unroll
  for (int j = 0; j < 8; ++j) o[j] = (short)f2bf(f[j]*inv);
  *(bf16x8*)p = o;
}

// ---------------- host ----------------
extern "C" void kernel_launch(void* const* d_in, const int* in_sizes, int n_in,
                              void* d_out, int out_size, void* d_ws, size_t ws_size,
                              hipStream_t stream)
{
  (void)in_sizes; (void)n_in; (void)out_size;
  constexpr long MB = 1l << 20;
  if (ws_size < 200*MB) return;  // layout needs 200 MiB; fail loudly via absmax

  const float* x0 = (const float*)d_in[0];
  const float* x1 = (const float*)d_in[1];
  const float* x2 = (const float*)d_in[2];
  const int*   ei = (const int*)d_in[3];
  const float* ew = (const float*)d_in[4];
  const float* Whd  = (const float*)d_in[17]; const float* bhd   = (const float*)d_in[18];
  const float* Win  = (const float*)d_in[19]; const float* bin   = (const float*)d_in[20];
  const float* Wout = (const float*)d_in[21]; const float* bout  = (const float*)d_in[22];
  const float* Wgt  = (const float*)d_in[23]; const float* bgate = (const float*)d_in[24];
  float* out = (float*)d_out;
  char* ws = (char*)d_ws;

  float*    deg    = (float*)(ws + 0);
  unsigned* cnt    = (unsigned*)(ws + 131072);
  unsigned* rowptr = (unsigned*)(ws + 262144);
  unsigned* curs   = (unsigned*)(ws + 524288);
  unsigned* csrc   = (unsigned*)(ws + 786432);
  float*    csrw   = (float*)(ws + 1835008);
  unsigned short* Weff = (unsigned short*)(ws + 2883584);   // 3 x [256][768]
  float*    beff   = (float*)(ws + 4063232);                // 3 x 256 f32
  float*    beq    = (float*)(ws + 4194304);                // 128 f32
  unsigned short* WIN   = (unsigned short*)(ws + 4456448);  // [1536][512] bf16
  unsigned short* WGTB  = (unsigned short*)(ws + 6029312);  // [128][512] bf16
  unsigned short* WHDT  = (unsigned short*)(ws + 6160384);  // [256][512] bf16 (Whd^T)
  unsigned short* WOUTT = (unsigned short*)(ws + 6422528);  // [512][512] bf16 (Wout^T)
  unsigned short* Wq2t  = (unsigned short*)(ws + 6946816);  // [1536][256] bf16 (Win*Whd)
  unsigned short* Weqt  = (unsigned short*)(ws + 7733248);  // [128][512] bf16 (Wgate*Wout)
  float*    PET4   = (float*)(ws + 7864320);                // [128][64][4] f32 (pe+bhd)^T
  float*    PEQ2   = (float*)(ws + 7995392);                // [64][1536] f32 (ends at 8MB)
  unsigned short* ZCAT3 = (unsigned short*)(ws + 40*MB);    // 3 x [32768][768] (40..184)
  unsigned short* AFUS  = (unsigned short*)(ws + 8*MB);     // [32768][256] 16MB (8..24)
  unsigned short* QKV   = (unsigned short*)(ws + 40*MB);    // [32768][1536] (40..136)
  unsigned short* VT    = (unsigned short*)(ws + 8*MB);     // [128][256][512] (8..40)
  unsigned short* SCOREB= (unsigned short*)(ws + 136*MB);   // [128][512][512] bf16 (136..200)
  unsigned short* CTX   = (unsigned short*)(ws + 40*MB);    // [512][32768] bf16 (40..72)

  // graph build
  hipMemsetAsync(deg,  0, 131072, stream);
  hipMemsetAsync(cnt,  0, 131072, stream);
  hipMemsetAsync(curs, 0, 131072, stream);
  histdeg_kernel<<<1024, 256, 0, stream>>>(ei, ew, cnt, deg);
  scan_kernel<<<1, 1024, 0, stream>>>(cnt, rowptr);
  scatter_kernel<<<1024, 256, 0, stream>>>(ei, ew, rowptr, curs, csrc, csrw);

  // weight prep
  weff3_kernel<<<dim3(768,3), 256, 0, stream>>>(
      (const float*)d_in[5], (const float*)d_in[9],  (const float*)d_in[13],
      (const float*)d_in[6], (const float*)d_in[10], (const float*)d_in[14],
      (const float*)d_in[7], (const float*)d_in[11], (const float*)d_in[15],
      (const float*)d_in[8], (const float*)d_in[12], (const float*)d_in[16],
      Weff, beff);
  cvt_f2b_kernel<<<3072, 256, 0, stream>>>(Win, WIN,  786432);
  cvt_f2b_kernel<<<256,  256, 0, stream>>>(Wgt, WGTB, 65536);
  tcvt_kernel<<<512,  256, 0, stream>>>(Whd,  WHDT,  8, 512);   // [512][256] -> [256][512]
  tcvt_kernel<<<1024, 256, 0, stream>>>(Wout, WOUTT, 9, 512);   // [512][512] -> ^T
  pe_kernel<<<128, 256, 0, stream>>>(bhd, PET4);

  // fused-weight precompute
  gemm_bt<0,2,0><<<dim3(2,12,1), 256, 0, stream>>>(WIN, WHDT, nullptr, Wq2t,
      512, 512, 512, 256, 0,0,0, 0, nullptr, nullptr, 1.0f);
  gemm_bt<0,2,0><<<dim3(4,1,1), 256, 0, stream>>>(WGTB, WOUTT, nullptr, Weqt,
      512, 512, 512, 512, 0,0,0, 0, nullptr, nullptr, 1.0f);
  peq2_kernel<<<384, 256, 0, stream>>>(Win, bin, PET4, PEQ2);
  beq_kernel<<<1, 128, 0, stream>>>(Wgt, bout, bgate, beq);

  // branches (z-batched): hop features then fused GEMM+GRU-activation -> out 0..2
  convx3_kernel<<<dim3(8192,1,3), 256, 0, stream>>>(x0, x1, x2, ZCAT3);
  prop3_kernel<0><<<dim3(8192,1,3), 256, 0, stream>>>(ZCAT3, rowptr, csrc, csrw, deg);
  prop3_kernel<1><<<dim3(8192,1,3), 256, 0, stream>>>(ZCAT3, rowptr, csrc, csrw, deg);
  gemm_bt<3,7,1><<<dim3(2,256,3), 256, 0, stream>>>(ZCAT3, Weff, out, nullptr,
      768, 768, 768, 128, ZSZE, 196608, OUTSEC, 0, beff, nullptr, 1.0f);

  // fusion gather, then fused uh+qkv GEMM (K=256, pe/bias row-table in epilogue)
  afus_kernel<<<dim3(4,2,64), 256, 0, stream>>>(out, AFUS);
  gemm_bt<0,5,1><<<dim3(12,256,1), 256, 0, stream>>>(AFUS, Wq2t, nullptr, QKV,
      256, 256, 256, 1536, 0,0,0, 0, nullptr, PEQ2, 1.0f);
  vt_kernel<<<dim3(32,128), 256, 0, stream>>>(QKV, VT);

  // attention, single shot z=128: bf16 scores -> in-place softmax -> ctx
  gemm_bt<1,2,1><<<dim3(4,4,128), 256, 0, stream>>>(QKV, QKV, nullptr, SCOREB,
      256, 98304, 98304, 512, 0,0,0, 0, nullptr, nullptr, 0.0625f);
  smax_kernel<<<16384, 256, 0, stream>>>(SCOREB);
  gemm_bt<2,2,1><<<dim3(2,4,128), 256, 0, stream>>>(SCOREB, VT, nullptr, CTX,
      512, 512, 512, 32768, 0,0,0, 0, nullptr, nullptr, 1.0f);

  // fused wout+wgate output GEMM (row remap (n,b) -> b*512+n in epilogue)
  gemm_bt<0,4,1><<<dim3(1,256,1), 256, 0, stream>>>(CTX, Weqt, out + 3*OUTSEC, nullptr,
      512, 512, 512, 128, 0,0,0, 0, beq, nullptr, 1.0f);
}